// Round 1
// baseline (153.144 us; speedup 1.0000x reference)
//
#include <hip/hip_runtime.h>

#define NROW 8192
#define DIM  1447
#define HD   64
#define KS   16
#define BM   256
#define BK   32

__device__ __forceinline__ float lrelu(float v) { return v >= 0.f ? v : 0.01f * v; }

// monotone float<->uint encoding for atomicMax on f32
__device__ __forceinline__ unsigned enc(float f) {
  unsigned u = __float_as_uint(f);
  return (u & 0x80000000u) ? ~u : (u | 0x80000000u);
}
__device__ __forceinline__ float dec(unsigned k) {
  unsigned u = (k & 0x80000000u) ? (k & 0x7fffffffu) : ~k;
  return __uint_as_float(u);
}

// K0: u1 = W_tr.T@a1, u2 = W_tr.T@a2, c1 = b_tr.a1, c2 = b_tr.a2; init M1 slot; zero rank[]
__global__ void k_prep(const float* __restrict__ Wtr, const float* __restrict__ btr,
                       const float* __restrict__ a, float* __restrict__ u12,
                       unsigned* __restrict__ m1slot, int* __restrict__ rank) {
  int t = threadIdx.x;  // 64 threads
  float u1 = 0.f, u2 = 0.f;
  for (int o = 0; o < 64; ++o) {
    float w = Wtr[o * 64 + t];
    u1 += w * a[o];
    u2 += w * a[64 + o];
  }
  u12[t] = u1;
  u12[64 + t] = u2;
  if (t == 0) {
    float c1 = 0.f, c2 = 0.f;
    for (int o = 0; o < 64; ++o) { c1 += btr[o] * a[o]; c2 += btr[o] * a[64 + o]; }
    u12[128] = c1; u12[129] = c2;
    *m1slot = 0u;
  }
  for (int i = t; i < NROW; i += 64) rank[i] = 0;
}

// K1: split-K partial GEMM: part[ks] += x[rows] @ W_fc.T  (256x64 tile / block)
__global__ __launch_bounds__(256) void k_gemm1(const float* __restrict__ x,
                                               const float* __restrict__ Wfc,
                                               float* __restrict__ part) {
  __shared__ alignas(16) float xs[BK][BM + 4];   // [kk][row]
  __shared__ alignas(16) float wsb[BK][HD + 4];  // [kk][col]
  int t = threadIdx.x;
  int ks = blockIdx.x & (KS - 1);
  int rb = blockIdx.x / KS;
  int tx = t & 7;    // cols tx*8 .. +7
  int ty = t >> 3;   // rows ty*8 .. +7  (ty in 0..31)
  const int CH = (DIM + KS - 1) / KS;  // 91
  int kbeg = ks * CH;
  int kend = kbeg + CH; if (kend > DIM) kend = DIM;
  float acc[8][8];
#pragma unroll
  for (int i = 0; i < 8; ++i)
#pragma unroll
    for (int j = 0; j < 8; ++j) acc[i][j] = 0.f;

  for (int kt = kbeg; kt < kend; kt += BK) {
    int tl = kend - kt; if (tl > BK) tl = BK;
#pragma unroll
    for (int i = 0; i < 32; ++i) {           // stage x tile (256 rows x 32 k)
      int idx = t + i * 256;
      int kk = idx & 31, row = idx >> 5;
      xs[kk][row] = (kk < tl) ? x[(rb * BM + row) * DIM + kt + kk] : 0.f;
    }
#pragma unroll
    for (int i = 0; i < 8; ++i) {            // stage W tile (64 cols x 32 k)
      int idx = t + i * 256;
      int kk = idx & 31, col = idx >> 5;
      wsb[kk][col] = (kk < tl) ? Wfc[col * DIM + kt + kk] : 0.f;
    }
    __syncthreads();
#pragma unroll
    for (int kk = 0; kk < BK; ++kk) {
      const float4* xp = (const float4*)&xs[kk][ty * 8];
      const float4* wp = (const float4*)&wsb[kk][tx * 8];
      float4 x0 = xp[0], x1 = xp[1];
      float4 w0 = wp[0], w1 = wp[1];
      float xr[8] = {x0.x, x0.y, x0.z, x0.w, x1.x, x1.y, x1.z, x1.w};
      float wc[8] = {w0.x, w0.y, w0.z, w0.w, w1.x, w1.y, w1.z, w1.w};
#pragma unroll
      for (int r = 0; r < 8; ++r)
#pragma unroll
        for (int c = 0; c < 8; ++c) acc[r][c] += xr[r] * wc[c];
    }
    __syncthreads();
  }
  float* pb = part + (size_t)ks * (NROW * HD);
#pragma unroll
  for (int r = 0; r < 8; ++r) {
    int row = rb * BM + ty * 8 + r;
    float4 v0 = make_float4(acc[r][0], acc[r][1], acc[r][2], acc[r][3]);
    float4 v1 = make_float4(acc[r][4], acc[r][5], acc[r][6], acc[r][7]);
    float4* dst = (float4*)&pb[row * HD + tx * 8];
    dst[0] = v0; dst[1] = v1;
  }
}

// K1b: h = lrelu(sum_ks part + b_fc)
__global__ void k_reduce1(const float* __restrict__ part, const float* __restrict__ bfc,
                          float* __restrict__ h) {
  int flat = blockIdx.x * 256 + threadIdx.x;
  float s = 0.f;
#pragma unroll
  for (int ks = 0; ks < KS; ++ks) s += part[(size_t)ks * (NROW * HD) + flat];
  s += bfc[flat & 63];
  h[flat] = lrelu(s);
}

// K2: s1 = h@u1 + c1, s2 = h@u2 + c2 ; global max(s1) via encoded atomicMax
__global__ void k_svec(const float* __restrict__ h, const float* __restrict__ u12,
                       float* __restrict__ s1, float* __restrict__ s2,
                       unsigned* __restrict__ m1slot) {
  int i = blockIdx.x * 256 + threadIdx.x;
  const float4* hr = (const float4*)(h + i * HD);
  float a1 = 0.f, a2 = 0.f;
#pragma unroll
  for (int q = 0; q < 16; ++q) {
    float4 v = hr[q];
    int c = q * 4;
    a1 += v.x * u12[c] + v.y * u12[c + 1] + v.z * u12[c + 2] + v.w * u12[c + 3];
    a2 += v.x * u12[64 + c] + v.y * u12[64 + c + 1] + v.z * u12[64 + c + 2] + v.w * u12[64 + c + 3];
  }
  float sv1 = a1 + u12[128];
  float sv2 = a2 + u12[129];
  s1[i] = sv1;
  s2[i] = sv2;
  float m = sv1;
#pragma unroll
  for (int off = 32; off > 0; off >>= 1) m = fmaxf(m, __shfl_xor(m, off));
  if ((threadIdx.x & 63) == 0) atomicMax(m1slot, enc(m));
}

// K3a: chunked rank counting (deterministic int atomics)
__global__ void k_count(const float* __restrict__ s1, int* __restrict__ rank) {
  __shared__ alignas(16) float scm[256];
  int t = threadIdx.x;
  int jb = blockIdx.x & 31;
  int ch = blockIdx.x >> 5;
  scm[t] = s1[ch * 256 + t];
  __syncthreads();
  int j = jb * 256 + t;
  float my = s1[j];
  int base = ch * 256;
  int cnt = 0;
#pragma unroll 8
  for (int q = 0; q < 256; q += 4) {
    float4 v = *(const float4*)&scm[q];
    cnt += (v.x < my) + (v.y < my) + (v.z < my) + (v.w < my);
    cnt += (v.x == my && (base + q) < j);
    cnt += (v.y == my && (base + q + 1) < j);
    cnt += (v.z == my && (base + q + 2) < j);
    cnt += (v.w == my && (base + q + 3) < j);
  }
  atomicAdd(&rank[j], cnt);
}

// K3b: scatter into sorted order
__global__ void k_scatter(const float* __restrict__ s1, const int* __restrict__ rank,
                          int* __restrict__ inv, float* __restrict__ s1s) {
  int j = blockIdx.x * 256 + threadIdx.x;
  int r = rank[j];
  inv[r] = j;
  s1s[r] = s1[j];
}

// K4: per-column prefix(B)/suffix(A) scans of weighted h (65 cols x 2 branches)
__global__ void k_scan(const int* __restrict__ inv, const float* __restrict__ s1s,
                       const float* __restrict__ h, const unsigned* __restrict__ m1slot,
                       float* __restrict__ SufA, float* __restrict__ PreB) {
  int t = threadIdx.x;
  int c = blockIdx.x % 65;
  int br = blockIdx.x / 65;  // 0 = A (suffix, e^{s1-M1}), 1 = B (prefix, e^{0.01 s1})
  float M1 = dec(*m1slot);
  float vals[32];
  int qb = t * 32;
#pragma unroll
  for (int e = 0; e < 32; ++e) {
    int q = qb + e;
    int r = br ? q : (NROW - 1 - q);
    int j = inv[r];
    float s = s1s[r];
    float w = br ? __expf(0.01f * s) : __expf(s - M1);
    float hv = (c < 64) ? h[j * HD + c] : 1.0f;
    vals[e] = w * hv;
  }
  float sum = 0.f;
#pragma unroll
  for (int e = 0; e < 32; ++e) sum += vals[e];
  int lane = t & 63, wid = t >> 6;
  float sc = sum;
#pragma unroll
  for (int off = 1; off < 64; off <<= 1) {
    float o = __shfl_up(sc, off);
    if (lane >= off) sc += o;
  }
  __shared__ float wt[4];
  if (lane == 63) wt[wid] = sc;
  __syncthreads();
  float woff = 0.f;
#pragma unroll
  for (int w = 0; w < 4; ++w)
    if (w < wid) woff += wt[w];
  float p = __shfl_up(sc, 1);
  float run = woff + (lane ? p : 0.f);  // exclusive prefix for this thread's chunk
  if (br) {
#pragma unroll
    for (int e = 0; e < 32; ++e) {
      int q = qb + e;
      PreB[q * 65 + c] = run;
      run += vals[e];
    }
    if (t == 255) PreB[NROW * 65 + c] = run;  // total
  } else {
#pragma unroll
    for (int e = 0; e < 32; ++e) {
      int q = qb + e;
      run += vals[e];
      SufA[(NROW - 1 - q) * 65 + c] = run;
    }
    if (t == 0) SufA[NROW * 65 + c] = 0.f;
  }
}

// K5: per-row: closed-form softmax combine + residual + W_f/lrelu + W_o
__global__ void k_final(const float* __restrict__ h, const float* __restrict__ s1s,
                        const float* __restrict__ s2, const float* __restrict__ SufA,
                        const float* __restrict__ PreB, const unsigned* __restrict__ m1slot,
                        const float* __restrict__ Wf, const float* __restrict__ bf,
                        const float* __restrict__ Wo, const float* __restrict__ bo,
                        float* __restrict__ out) {
  int t = threadIdx.x;
  int lane = t & 63, wid = t >> 6;
  int i = blockIdx.x * 4 + wid;
  float M1 = dec(*m1slot);
  float s2i = s2[i];
  float th = -s2i;
  float z = s2i + M1;
  float mi = lrelu(z);              // row max of lrelu(scores) (lrelu monotone)
  float cA = __expf(z - mi);
  float cB = __expf(0.01f * s2i - mi);
  // 3-round wave-parallel lower_bound: cnt = #{ s1 < th }
  float v1 = s1s[lane * 128];
  int n1 = __popcll(__ballot(v1 < th));
  int cnt = 0;
  if (n1 > 0) {
    int L = (n1 - 1) * 128;
    float v2 = s1s[L + 1 + 2 * lane];
    int n2 = __popcll(__ballot(v2 < th));
    cnt = L + 2 * n2;
    if (cnt < NROW && s1s[cnt] < th) cnt++;
  }
  const float* ra = SufA + cnt * 65;
  const float* rb = PreB + cnt * 65;
  float vA = ra[lane], vB = rb[lane];
  float zA = ra[64], zB = rb[64];
  float Z = cA * zA + cB * zB;     // >= 1 by max-shift
  float h2 = (cA * vA + cB * vB) / Z + h[i * HD + lane];
  // h3[o=lane] = lrelu(sum_c Wf[o][c]*h2[c] + bf[o]) via shfl broadcast
  const float4* wrow = (const float4*)(Wf + lane * HD);
  float acc = bf[lane];
#pragma unroll
  for (int q = 0; q < 16; ++q) {
    float4 wv = wrow[q];
    int c = q * 4;
    acc += wv.x * __shfl(h2, c) + wv.y * __shfl(h2, c + 1) +
           wv.z * __shfl(h2, c + 2) + wv.w * __shfl(h2, c + 3);
  }
  float h3 = lrelu(acc);
  float pv = h3 * Wo[lane];
#pragma unroll
  for (int off = 32; off > 0; off >>= 1) pv += __shfl_xor(pv, off);
  if (lane == 0) out[i] = pv + bo[0];
}

extern "C" void kernel_launch(void* const* d_in, const int* in_sizes, int n_in,
                              void* d_out, int out_size, void* d_ws, size_t ws_size,
                              hipStream_t stream) {
  const float* x   = (const float*)d_in[0];
  const float* Wfc = (const float*)d_in[1];
  const float* bfc = (const float*)d_in[2];
  const float* Wtr = (const float*)d_in[3];
  const float* btr = (const float*)d_in[4];
  const float* a   = (const float*)d_in[5];
  const float* Wf  = (const float*)d_in[6];
  const float* bf  = (const float*)d_in[7];
  const float* Wo  = (const float*)d_in[8];
  const float* bo  = (const float*)d_in[9];
  float* out = (float*)d_out;

  char* w = (char*)d_ws;
  size_t off = 0;
  auto alloc = [&](size_t bytes) -> void* {
    void* p = w + off;
    off = (off + bytes + 255) & ~(size_t)255;
    return p;
  };
  float* h      = (float*)alloc((size_t)NROW * HD * 4);
  float* s1     = (float*)alloc(NROW * 4);
  float* s2     = (float*)alloc(NROW * 4);
  float* u12    = (float*)alloc(130 * 4);
  unsigned* m1  = (unsigned*)alloc(4);
  int* rank     = (int*)alloc(NROW * 4);
  int* inv      = (int*)alloc(NROW * 4);
  float* s1s    = (float*)alloc(NROW * 4);
  char* big     = (char*)alloc((size_t)KS * NROW * HD * 4);  // 33.5 MB
  float* part = (float*)big;                   // used K1..K1b
  float* SufA = (float*)big;                   // reuses big after K1b
  float* PreB = SufA + (size_t)(NROW + 1) * 65;
  (void)in_sizes; (void)n_in; (void)out_size; (void)ws_size;

  k_prep<<<1, 64, 0, stream>>>(Wtr, btr, a, u12, m1, rank);
  k_gemm1<<<(NROW / BM) * KS, 256, 0, stream>>>(x, Wfc, part);
  k_reduce1<<<NROW * HD / 256, 256, 0, stream>>>(part, bfc, h);
  k_svec<<<NROW / 256, 256, 0, stream>>>(h, u12, s1, s2, m1);
  k_count<<<32 * 32, 256, 0, stream>>>(s1, rank);
  k_scatter<<<NROW / 256, 256, 0, stream>>>(s1, rank, inv, s1s);
  k_scan<<<130, 256, 0, stream>>>(inv, s1s, h, m1, SufA, PreB);
  k_final<<<NROW / 4, 256, 0, stream>>>(h, s1s, s2, SufA, PreB, m1, Wf, bf, Wo, bo, out);
}

// Round 2
// 151.378 us; speedup vs baseline: 1.0117x; 1.0117x over previous
//
#include <hip/hip_runtime.h>

#define NROW 8192
#define DIM  1447
#define HD   64
#define KS   16
#define CH   91      // ceil(DIM/KS)
#define BM   128
#define BK   32
#define SP   8200    // transposed scan row stride (>= NROW+1)

__device__ __forceinline__ float lrelu(float v) { return v >= 0.f ? v : 0.01f * v; }

// monotone float<->uint encoding for atomicMax on f32
__device__ __forceinline__ unsigned enc(float f) {
  unsigned u = __float_as_uint(f);
  return (u & 0x80000000u) ? ~u : (u | 0x80000000u);
}
__device__ __forceinline__ float dec(unsigned k) {
  unsigned u = (k & 0x80000000u) ? (k & 0x7fffffffu) : ~k;
  return __uint_as_float(u);
}

// K0: u1 = W_tr.T@a1, u2 = W_tr.T@a2, c1 = b_tr.a1, c2 = b_tr.a2; init M1; zero rank[]
__global__ void k_prep(const float* __restrict__ Wtr, const float* __restrict__ btr,
                       const float* __restrict__ a, float* __restrict__ u12,
                       unsigned* __restrict__ m1slot, int* __restrict__ rank) {
  int t = threadIdx.x;  // 64 threads
  float u1 = 0.f, u2 = 0.f;
  for (int o = 0; o < 64; ++o) {
    float w = Wtr[o * 64 + t];
    u1 += w * a[o];
    u2 += w * a[64 + o];
  }
  u12[t] = u1;
  u12[64 + t] = u2;
  if (t == 0) {
    float c1 = 0.f, c2 = 0.f;
    for (int o = 0; o < 64; ++o) { c1 += btr[o] * a[o]; c2 += btr[o] * a[64 + o]; }
    u12[128] = c1; u12[129] = c2;
    *m1slot = 0u;
  }
  for (int i = t; i < NROW; i += 64) rank[i] = 0;
}

// K1: split-K partial GEMM. 128x64 tile, 256 threads, 4x8 thread tile.
// grid = (NROW/BM) * KS = 64*16 = 1024 blocks -> ~4 blocks/CU resident.
__global__ __launch_bounds__(256, 4) void k_gemm1(const float* __restrict__ x,
                                                  const float* __restrict__ Wfc,
                                                  float* __restrict__ part) {
  __shared__ alignas(16) float xs[BK][BM + 4];   // [kk][row], 132 floats/row
  __shared__ alignas(16) float wsb[BK][HD + 4];  // [kk][col], 68 floats/row
  int t = threadIdx.x;
  int ks = blockIdx.x & (KS - 1);
  int rb = blockIdx.x >> 4;
  int rowg = t >> 3;   // 0..31 -> rows rowg*4..+3
  int colg = t & 7;    // 0..7  -> cols colg*8..+7
  int kbeg = ks * CH;
  int kend = kbeg + CH; if (kend > DIM) kend = DIM;
  float acc[4][8];
#pragma unroll
  for (int r = 0; r < 4; ++r)
#pragma unroll
    for (int c = 0; c < 8; ++c) acc[r][c] = 0.f;

  for (int kt = kbeg; kt < kend; kt += BK) {
    int tl = kend - kt; if (tl > BK) tl = BK;
#pragma unroll
    for (int i = 0; i < 16; ++i) {           // stage x tile: 128 rows x 32 k
      int idx = t + i * 256;
      int kk = idx & 31, row = idx >> 5;
      xs[kk][row] = (kk < tl) ? x[(size_t)(rb * BM + row) * DIM + kt + kk] : 0.f;
    }
#pragma unroll
    for (int i = 0; i < 8; ++i) {            // stage W tile: 64 cols x 32 k
      int idx = t + i * 256;
      int kk = idx & 31, col = idx >> 5;
      wsb[kk][col] = (kk < tl) ? Wfc[(size_t)col * DIM + kt + kk] : 0.f;
    }
    __syncthreads();
#pragma unroll
    for (int kk = 0; kk < BK; ++kk) {
      float4 xv = *(const float4*)&xs[kk][rowg * 4];
      const float4* wp = (const float4*)&wsb[kk][colg * 8];
      float4 w0 = wp[0], w1 = wp[1];
      float xr[4] = {xv.x, xv.y, xv.z, xv.w};
      float wc[8] = {w0.x, w0.y, w0.z, w0.w, w1.x, w1.y, w1.z, w1.w};
#pragma unroll
      for (int r = 0; r < 4; ++r)
#pragma unroll
        for (int c = 0; c < 8; ++c) acc[r][c] += xr[r] * wc[c];
    }
    __syncthreads();
  }
  float* pb = part + (size_t)ks * (NROW * HD);
#pragma unroll
  for (int r = 0; r < 4; ++r) {
    int row = rb * BM + rowg * 4 + r;
    float4* dst = (float4*)&pb[(size_t)row * HD + colg * 8];
    dst[0] = make_float4(acc[r][0], acc[r][1], acc[r][2], acc[r][3]);
    dst[1] = make_float4(acc[r][4], acc[r][5], acc[r][6], acc[r][7]);
  }
}

// K2 (fused reduce+svec): h = lrelu(sum_ks part + b_fc); s1 = h@u1+c1, s2 = h@u2+c2; max(s1)
// 256 blocks x 256 thr; 32 rows/block; 8 threads/row (8 cols each).
__global__ void k_hsv(const float* __restrict__ part, const float* __restrict__ bfc,
                      const float* __restrict__ u12, float* __restrict__ h,
                      float* __restrict__ s1, float* __restrict__ s2,
                      unsigned* __restrict__ m1slot) {
  int t = threadIdx.x;
  int r = blockIdx.x * 32 + (t >> 3);
  int cg = t & 7;
  size_t base = (size_t)r * HD + cg * 8;
  float v[8];
#pragma unroll
  for (int j = 0; j < 8; ++j) v[j] = 0.f;
#pragma unroll
  for (int ks = 0; ks < KS; ++ks) {
    const float4* p = (const float4*)&part[(size_t)ks * (NROW * HD) + base];
    float4 q0 = p[0], q1 = p[1];
    v[0] += q0.x; v[1] += q0.y; v[2] += q0.z; v[3] += q0.w;
    v[4] += q1.x; v[5] += q1.y; v[6] += q1.z; v[7] += q1.w;
  }
  float d1 = 0.f, d2 = 0.f;
#pragma unroll
  for (int j = 0; j < 8; ++j) {
    int c = cg * 8 + j;
    float hv = lrelu(v[j] + bfc[c]);
    v[j] = hv;
    d1 += hv * u12[c];
    d2 += hv * u12[64 + c];
  }
  float4* hw = (float4*)&h[base];
  hw[0] = make_float4(v[0], v[1], v[2], v[3]);
  hw[1] = make_float4(v[4], v[5], v[6], v[7]);
#pragma unroll
  for (int off = 1; off < 8; off <<= 1) {
    d1 += __shfl_xor(d1, off);
    d2 += __shfl_xor(d2, off);
  }
  float sv1 = d1 + u12[128];
  float sv2 = d2 + u12[129];
  if (cg == 0) { s1[r] = sv1; s2[r] = sv2; }
  float m = sv1;
#pragma unroll
  for (int off = 8; off < 64; off <<= 1) m = fmaxf(m, __shfl_xor(m, off));
  if ((t & 63) == 0) atomicMax(m1slot, enc(m));
}

// K3a: chunked rank counting (deterministic int atomics)
__global__ void k_count(const float* __restrict__ s1, int* __restrict__ rank) {
  __shared__ alignas(16) float scm[256];
  int t = threadIdx.x;
  int jb = blockIdx.x & 31;
  int ch = blockIdx.x >> 5;
  scm[t] = s1[ch * 256 + t];
  __syncthreads();
  int j = jb * 256 + t;
  float my = s1[j];
  int base = ch * 256;
  int cnt = 0;
#pragma unroll 8
  for (int q = 0; q < 256; q += 4) {
    float4 v = *(const float4*)&scm[q];
    cnt += (v.x < my) + (v.y < my) + (v.z < my) + (v.w < my);
    cnt += (v.x == my && (base + q) < j);
    cnt += (v.y == my && (base + q + 1) < j);
    cnt += (v.z == my && (base + q + 2) < j);
    cnt += (v.w == my && (base + q + 3) < j);
  }
  atomicAdd(&rank[j], cnt);
}

// K3b: scatter into sorted order
__global__ void k_scatter(const float* __restrict__ s1, const int* __restrict__ rank,
                          int* __restrict__ inv, float* __restrict__ s1s) {
  int j = blockIdx.x * 256 + threadIdx.x;
  int r = rank[j];
  inv[r] = j;
  s1s[r] = s1[j];
}

// K4: per-column prefix(B)/suffix(A) scans, TRANSPOSED output [c][q] (stride SP)
// 130 blocks x 512 threads, 16 elems/thread -> lane-contiguous 64B writes.
__global__ void k_scan(const int* __restrict__ inv, const float* __restrict__ s1s,
                       const float* __restrict__ h, const unsigned* __restrict__ m1slot,
                       float* __restrict__ SufA, float* __restrict__ PreB) {
  int t = threadIdx.x;
  int c = blockIdx.x % 65;
  int br = blockIdx.x / 65;  // 0 = A (suffix, e^{s1-M1}), 1 = B (prefix, e^{0.01 s1})
  float M1 = dec(*m1slot);
  float vals[16];
  int qb = t * 16;
#pragma unroll
  for (int e = 0; e < 16; ++e) {
    int q = qb + e;
    int r = br ? q : (NROW - 1 - q);
    int j = inv[r];
    float s = s1s[r];
    float w = br ? __expf(0.01f * s) : __expf(s - M1);
    float hv = (c < 64) ? h[j * HD + c] : 1.0f;
    vals[e] = w * hv;
  }
  float sum = 0.f;
#pragma unroll
  for (int e = 0; e < 16; ++e) sum += vals[e];
  int lane = t & 63, wid = t >> 6;
  float sc = sum;
#pragma unroll
  for (int off = 1; off < 64; off <<= 1) {
    float o = __shfl_up(sc, off);
    if (lane >= off) sc += o;
  }
  __shared__ float wt[8];
  if (lane == 63) wt[wid] = sc;
  __syncthreads();
  float woff = 0.f;
#pragma unroll
  for (int w = 0; w < 8; ++w)
    if (w < wid) woff += wt[w];
  float p = __shfl_up(sc, 1);
  float run = woff + (lane ? p : 0.f);  // exclusive prefix of this thread's chunk
  if (br) {
    float* pb = PreB + (size_t)c * SP;
#pragma unroll
    for (int e = 0; e < 16; ++e) {
      pb[qb + e] = run;
      run += vals[e];
    }
    if (t == 511) pb[NROW] = run;  // total
  } else {
    float* sa = SufA + (size_t)c * SP;
#pragma unroll
    for (int e = 0; e < 16; ++e) {
      run += vals[e];
      sa[NROW - 1 - (qb + e)] = run;
    }
    if (t == 0) sa[NROW] = 0.f;
  }
}

// K5: per-row closed-form softmax combine + residual + W_f/lrelu + W_o
__global__ void k_final(const float* __restrict__ h, const float* __restrict__ s1s,
                        const float* __restrict__ s2, const float* __restrict__ SufA,
                        const float* __restrict__ PreB, const unsigned* __restrict__ m1slot,
                        const float* __restrict__ Wf, const float* __restrict__ bf,
                        const float* __restrict__ Wo, const float* __restrict__ bo,
                        float* __restrict__ out) {
  int t = threadIdx.x;
  int lane = t & 63, wid = t >> 6;
  int i = blockIdx.x * 4 + wid;
  float M1 = dec(*m1slot);
  float s2i = s2[i];
  float th = -s2i;
  float z = s2i + M1;
  float mi = lrelu(z);              // row max of lrelu(scores) (lrelu monotone)
  float cA = __expf(z - mi);
  float cB = __expf(0.01f * s2i - mi);
  // wave-parallel lower_bound: cnt = #{ s1 < th }
  float v1 = s1s[lane * 128];
  int n1 = __popcll(__ballot(v1 < th));
  int cnt = 0;
  if (n1 > 0) {
    int L = (n1 - 1) * 128;
    float v2 = s1s[L + 1 + 2 * lane];
    int n2 = __popcll(__ballot(v2 < th));
    cnt = L + 2 * n2;
    if (cnt < NROW && s1s[cnt] < th) cnt++;
  }
  float vA = SufA[(size_t)lane * SP + cnt];
  float vB = PreB[(size_t)lane * SP + cnt];
  float zA = SufA[(size_t)64 * SP + cnt];
  float zB = PreB[(size_t)64 * SP + cnt];
  float Z = cA * zA + cB * zB;
  float h2 = (cA * vA + cB * vB) / Z + h[i * HD + lane];
  const float4* wrow = (const float4*)(Wf + lane * HD);
  float acc = bf[lane];
#pragma unroll
  for (int q = 0; q < 16; ++q) {
    float4 wv = wrow[q];
    int c = q * 4;
    acc += wv.x * __shfl(h2, c) + wv.y * __shfl(h2, c + 1) +
           wv.z * __shfl(h2, c + 2) + wv.w * __shfl(h2, c + 3);
  }
  float h3 = lrelu(acc);
  float pv = h3 * Wo[lane];
#pragma unroll
  for (int off = 32; off > 0; off >>= 1) pv += __shfl_xor(pv, off);
  if (lane == 0) out[i] = pv + bo[0];
}

extern "C" void kernel_launch(void* const* d_in, const int* in_sizes, int n_in,
                              void* d_out, int out_size, void* d_ws, size_t ws_size,
                              hipStream_t stream) {
  const float* x   = (const float*)d_in[0];
  const float* Wfc = (const float*)d_in[1];
  const float* bfc = (const float*)d_in[2];
  const float* Wtr = (const float*)d_in[3];
  const float* btr = (const float*)d_in[4];
  const float* a   = (const float*)d_in[5];
  const float* Wf  = (const float*)d_in[6];
  const float* bf  = (const float*)d_in[7];
  const float* Wo  = (const float*)d_in[8];
  const float* bo  = (const float*)d_in[9];
  float* out = (float*)d_out;

  char* w = (char*)d_ws;
  size_t off = 0;
  auto alloc = [&](size_t bytes) -> void* {
    void* p = w + off;
    off = (off + bytes + 255) & ~(size_t)255;
    return p;
  };
  float* h      = (float*)alloc((size_t)NROW * HD * 4);
  float* s1     = (float*)alloc(NROW * 4);
  float* s2     = (float*)alloc(NROW * 4);
  float* u12    = (float*)alloc(130 * 4);
  unsigned* m1  = (unsigned*)alloc(4);
  int* rank     = (int*)alloc(NROW * 4);
  int* inv      = (int*)alloc(NROW * 4);
  float* s1s    = (float*)alloc(NROW * 4);
  char* big     = (char*)alloc((size_t)KS * NROW * HD * 4);  // 33.5 MB
  float* part = (float*)big;                    // used K1..K2
  float* SufA = (float*)big;                    // reuses big after K2 ([65][SP])
  float* PreB = SufA + (size_t)65 * SP;         // [65][SP]
  (void)in_sizes; (void)n_in; (void)out_size; (void)ws_size;

  k_prep<<<1, 64, 0, stream>>>(Wtr, btr, a, u12, m1, rank);
  k_gemm1<<<(NROW / BM) * KS, 256, 0, stream>>>(x, Wfc, part);
  k_hsv<<<NROW / 32, 256, 0, stream>>>(part, bfc, u12, h, s1, s2, m1);
  k_count<<<32 * 32, 256, 0, stream>>>(s1, rank);
  k_scatter<<<NROW / 256, 256, 0, stream>>>(s1, rank, inv, s1s);
  k_scan<<<130, 512, 0, stream>>>(inv, s1s, h, m1, SufA, PreB);
  k_final<<<NROW / 4, 256, 0, stream>>>(h, s1s, s2, SufA, PreB, m1, Wf, bf, Wo, bo, out);
}

// Round 3
// 105.065 us; speedup vs baseline: 1.4576x; 1.4408x over previous
//
#include <hip/hip_runtime.h>

#define NROW 8192
#define DIM  1447
#define HD   64
#define WK   1472      // 23*64: zero-padded K for pre-converted W
#define NSTEP 23
#define SP   8200      // scan row stride (>= NROW+1)

typedef __attribute__((ext_vector_type(8))) short bf16x8;
typedef __attribute__((ext_vector_type(4))) float f32x4;

__device__ __forceinline__ float lrelu(float v) { return v >= 0.f ? v : 0.01f * v; }

__device__ __forceinline__ unsigned short f2bf(float f) {
  unsigned u = __float_as_uint(f);
  u = u + 0x7fffu + ((u >> 16) & 1u);   // RNE
  return (unsigned short)(u >> 16);
}
__device__ __forceinline__ float bf2f(unsigned short s) {
  return __uint_as_float((unsigned)s << 16);
}

// monotone float<->uint encoding for atomicMax on f32
__device__ __forceinline__ unsigned enc(float f) {
  unsigned u = __float_as_uint(f);
  return (u & 0x80000000u) ? ~u : (u | 0x80000000u);
}
__device__ __forceinline__ float dec(unsigned k) {
  unsigned u = (k & 0x80000000u) ? (k & 0x7fffffffu) : ~k;
  return __uint_as_float(u);
}

// K0: block 0: u1/u2/c1/c2 prep, zero rank, init M1.  blocks 1..368: W_fc -> bf16 hi/lo (K-padded)
__global__ void k_prep(const float* __restrict__ Wtr, const float* __restrict__ btr,
                       const float* __restrict__ a, const float* __restrict__ Wfc,
                       float* __restrict__ u12, unsigned* __restrict__ m1slot,
                       int* __restrict__ rank, unsigned short* __restrict__ Wh,
                       unsigned short* __restrict__ Wl) {
  int t = threadIdx.x;
  int b = blockIdx.x;
  if (b == 0) {
    if (t < 64) {
      float u1 = 0.f, u2 = 0.f;
      for (int o = 0; o < 64; ++o) {
        float w = Wtr[o * 64 + t];
        u1 += w * a[o];
        u2 += w * a[64 + o];
      }
      u12[t] = u1; u12[64 + t] = u2;
      if (t == 0) {
        float c1 = 0.f, c2 = 0.f;
        for (int o = 0; o < 64; ++o) { c1 += btr[o] * a[o]; c2 += btr[o] * a[64 + o]; }
        u12[128] = c1; u12[129] = c2;
        *m1slot = 0u;
      }
    }
    for (int i = t; i < NROW; i += 256) rank[i] = 0;
  } else {
    int idx = (b - 1) * 256 + t;          // < 64*WK
    int c = idx / WK, k = idx - c * WK;
    float v = (k < DIM) ? Wfc[c * DIM + k] : 0.f;
    unsigned short hi = f2bf(v);
    Wh[idx] = hi;
    Wl[idx] = f2bf(v - bf2f(hi));
  }
}

// K1: h = lrelu(x @ W_fc.T + b_fc) via split-bf16 MFMA (3-term Markidis).
// 256 blocks x 512 thr (8 waves). Tile 32 rows x 64 cols, BK=64, double-buffered LDS.
__global__ __launch_bounds__(512) void k_gemm1(const float* __restrict__ x,
    const unsigned short* __restrict__ Wh, const unsigned short* __restrict__ Wl,
    const float* __restrict__ bfc, float* __restrict__ h) {
  __shared__ alignas(16) unsigned short Ah[2][32][72], Al[2][32][72];
  __shared__ alignas(16) unsigned short Bh[2][64][72], Bl[2][64][72];
  int t = threadIdx.x;
  int rb = blockIdx.x;
  // staging: x tile 32x64 f32 -> 4 elems/thread; W tile 64x64 bf16(hi+lo) -> 8/thread each
  int sxr = t >> 4;            // 0..31 row
  int sxk = (t & 15) * 4;      // 0..60
  int swc = t >> 3;            // 0..63 col
  int swk = (t & 7) * 8;       // 0..56
  // wave -> output sub-tile
  int wv = t >> 6;             // 0..7
  int rg = (wv & 1) * 16;
  int cg = (wv >> 1) * 16;
  int l = t & 63;
  int l15 = l & 15;
  int l4 = l >> 4;

  const float* xrow = x + (size_t)(rb * 32 + sxr) * DIM;
  const unsigned short* whrow = Wh + (size_t)swc * WK + swk;
  const unsigned short* wlrow = Wl + (size_t)swc * WK + swk;

  f32x4 acc = {0.f, 0.f, 0.f, 0.f};
  float x0, x1, x2, x3;
  int4 wh4, wl4;

  // prologue: load step 0 (x rows are only 4B-aligned: DIM odd -> scalar loads)
  x0 = xrow[sxk]; x1 = xrow[sxk + 1]; x2 = xrow[sxk + 2]; x3 = xrow[sxk + 3];
  wh4 = *(const int4*)&whrow[0];
  wl4 = *(const int4*)&wlrow[0];
  {
    unsigned short h0 = f2bf(x0), h1 = f2bf(x1), h2 = f2bf(x2), h3 = f2bf(x3);
    unsigned short m0 = f2bf(x0 - bf2f(h0)), m1_ = f2bf(x1 - bf2f(h1)),
                   m2 = f2bf(x2 - bf2f(h2)), m3 = f2bf(x3 - bf2f(h3));
    uint2 ph, pl;
    ph.x = (unsigned)h0 | ((unsigned)h1 << 16);
    ph.y = (unsigned)h2 | ((unsigned)h3 << 16);
    pl.x = (unsigned)m0 | ((unsigned)m1_ << 16);
    pl.y = (unsigned)m2 | ((unsigned)m3 << 16);
    *(uint2*)&Ah[0][sxr][sxk] = ph;
    *(uint2*)&Al[0][sxr][sxk] = pl;
    *(int4*)&Bh[0][swc][swk] = wh4;
    *(int4*)&Bl[0][swc][swk] = wl4;
  }
  __syncthreads();

  for (int s = 0; s < NSTEP; ++s) {
    int buf = s & 1;
    if (s + 1 < NSTEP) {               // issue next-step global loads early
      int kt = (s + 1) * 64;
      int kg = kt + sxk;
      x0 = (kg     < DIM) ? xrow[kg]     : 0.f;
      x1 = (kg + 1 < DIM) ? xrow[kg + 1] : 0.f;
      x2 = (kg + 2 < DIM) ? xrow[kg + 2] : 0.f;
      x3 = (kg + 3 < DIM) ? xrow[kg + 3] : 0.f;
      wh4 = *(const int4*)&whrow[kt];
      wl4 = *(const int4*)&wlrow[kt];
    }
#pragma unroll
    for (int c = 0; c < 2; ++c) {
      int kc = c * 32 + l4 * 8;
      bf16x8 fah = *(const bf16x8*)&Ah[buf][rg + l15][kc];
      bf16x8 fal = *(const bf16x8*)&Al[buf][rg + l15][kc];
      bf16x8 fbh = *(const bf16x8*)&Bh[buf][cg + l15][kc];
      bf16x8 fbl = *(const bf16x8*)&Bl[buf][cg + l15][kc];
      acc = __builtin_amdgcn_mfma_f32_16x16x32_bf16(fah, fbh, acc, 0, 0, 0);
      acc = __builtin_amdgcn_mfma_f32_16x16x32_bf16(fah, fbl, acc, 0, 0, 0);
      acc = __builtin_amdgcn_mfma_f32_16x16x32_bf16(fal, fbh, acc, 0, 0, 0);
    }
    if (s + 1 < NSTEP) {               // convert + write the other buffer
      int nb = buf ^ 1;
      unsigned short h0 = f2bf(x0), h1 = f2bf(x1), h2 = f2bf(x2), h3 = f2bf(x3);
      unsigned short m0 = f2bf(x0 - bf2f(h0)), m1_ = f2bf(x1 - bf2f(h1)),
                     m2 = f2bf(x2 - bf2f(h2)), m3 = f2bf(x3 - bf2f(h3));
      uint2 ph, pl;
      ph.x = (unsigned)h0 | ((unsigned)h1 << 16);
      ph.y = (unsigned)h2 | ((unsigned)h3 << 16);
      pl.x = (unsigned)m0 | ((unsigned)m1_ << 16);
      pl.y = (unsigned)m2 | ((unsigned)m3 << 16);
      *(uint2*)&Ah[nb][sxr][sxk] = ph;
      *(uint2*)&Al[nb][sxr][sxk] = pl;
      *(int4*)&Bh[nb][swc][swk] = wh4;
      *(int4*)&Bl[nb][swc][swk] = wl4;
    }
    __syncthreads();
  }

  // epilogue: bias + lrelu + store.  D: col = lane&15, row = 4*(lane>>4)+reg  [m89-verified]
  int col = cg + l15;
  float bb = bfc[col];
  int row0 = rb * 32 + rg + l4 * 4;
#pragma unroll
  for (int r = 0; r < 4; ++r) {
    h[(size_t)(row0 + r) * HD + col] = lrelu(acc[r] + bb);
  }
}

// K2: s1 = h@u1+c1, s2 = h@u2+c2, global max(s1).  32 rows/block, 8 thr/row.
__global__ void k_hsv(const float* __restrict__ h, const float* __restrict__ u12,
                      float* __restrict__ s1, float* __restrict__ s2,
                      unsigned* __restrict__ m1slot) {
  int t = threadIdx.x;
  int r = blockIdx.x * 32 + (t >> 3);
  int cg = t & 7;
  const float4* p = (const float4*)&h[(size_t)r * HD + cg * 8];
  float4 q0 = p[0], q1 = p[1];
  float v[8] = {q0.x, q0.y, q0.z, q0.w, q1.x, q1.y, q1.z, q1.w};
  float d1 = 0.f, d2 = 0.f;
#pragma unroll
  for (int j = 0; j < 8; ++j) {
    int c = cg * 8 + j;
    d1 += v[j] * u12[c];
    d2 += v[j] * u12[64 + c];
  }
#pragma unroll
  for (int off = 1; off < 8; off <<= 1) {
    d1 += __shfl_xor(d1, off);
    d2 += __shfl_xor(d2, off);
  }
  float sv1 = d1 + u12[128];
  float sv2 = d2 + u12[129];
  if (cg == 0) { s1[r] = sv1; s2[r] = sv2; }
  float m = sv1;
#pragma unroll
  for (int off = 8; off < 64; off <<= 1) m = fmaxf(m, __shfl_xor(m, off));
  if ((t & 63) == 0) atomicMax(m1slot, enc(m));
}

// K3a: chunked rank counting (deterministic int atomics)
__global__ void k_count(const float* __restrict__ s1, int* __restrict__ rank) {
  __shared__ alignas(16) float scm[256];
  int t = threadIdx.x;
  int jb = blockIdx.x & 31;
  int ch = blockIdx.x >> 5;
  scm[t] = s1[ch * 256 + t];
  __syncthreads();
  int j = jb * 256 + t;
  float my = s1[j];
  int base = ch * 256;
  int cnt = 0;
#pragma unroll 8
  for (int q = 0; q < 256; q += 4) {
    float4 v = *(const float4*)&scm[q];
    cnt += (v.x < my) + (v.y < my) + (v.z < my) + (v.w < my);
    cnt += (v.x == my && (base + q) < j);
    cnt += (v.y == my && (base + q + 1) < j);
    cnt += (v.z == my && (base + q + 2) < j);
    cnt += (v.w == my && (base + q + 3) < j);
  }
  atomicAdd(&rank[j], cnt);
}

// K3b: scatter into sorted order
__global__ void k_scatter(const float* __restrict__ s1, const int* __restrict__ rank,
                          int* __restrict__ inv, float* __restrict__ s1s) {
  int j = blockIdx.x * 256 + threadIdx.x;
  int r = rank[j];
  inv[r] = j;
  s1s[r] = s1[j];
}

// K3c: hsT[c][r] = h[inv[r]][c]  (gather once, coalesced; scan then reads streams)
__global__ void k_trans(const float* __restrict__ h, const int* __restrict__ inv,
                        float* __restrict__ hsT) {
  __shared__ float tile[128][64];
  int t = threadIdx.x;
  int r0 = blockIdx.x * 128;
  int rr = t >> 4;
  int cq = (t & 15) * 4;
#pragma unroll
  for (int p = 0; p < 8; ++p) {
    int r = p * 16 + rr;
    int j = inv[r0 + r];
    *(float4*)&tile[r][cq] = *(const float4*)&h[(size_t)j * HD + cq];
  }
  __syncthreads();
  int c = t >> 2;
  int seg = (t & 3) * 32;
#pragma unroll
  for (int e = 0; e < 32; e += 4) {
    int r = seg + e;
    float4 v = make_float4(tile[r][c], tile[r + 1][c], tile[r + 2][c], tile[r + 3][c]);
    *(float4*)&hsT[(size_t)c * NROW + r0 + r] = v;
  }
}

// K4: per-column prefix(B)/suffix(A) scans over sorted order, output [c][q] stride SP
__global__ void k_scan(const float* __restrict__ s1s, const float* __restrict__ hsT,
                       const unsigned* __restrict__ m1slot,
                       float* __restrict__ SufA, float* __restrict__ PreB) {
  int t = threadIdx.x;
  int c = blockIdx.x % 65;
  int br = blockIdx.x / 65;  // 0 = A (suffix, e^{s1-M1}), 1 = B (prefix, e^{0.01 s1})
  float M1 = dec(*m1slot);
  const float* hc = hsT + (size_t)c * NROW;
  float vals[16];
  int qb = t * 16;
#pragma unroll
  for (int e = 0; e < 16; ++e) {
    int q = qb + e;
    int r = br ? q : (NROW - 1 - q);
    float s = s1s[r];
    float w = br ? __expf(0.01f * s) : __expf(s - M1);
    float hv = (c < 64) ? hc[r] : 1.0f;
    vals[e] = w * hv;
  }
  float sum = 0.f;
#pragma unroll
  for (int e = 0; e < 16; ++e) sum += vals[e];
  int lane = t & 63, wid = t >> 6;
  float sc = sum;
#pragma unroll
  for (int off = 1; off < 64; off <<= 1) {
    float o = __shfl_up(sc, off);
    if (lane >= off) sc += o;
  }
  __shared__ float wt[8];
  if (lane == 63) wt[wid] = sc;
  __syncthreads();
  float woff = 0.f;
#pragma unroll
  for (int w = 0; w < 8; ++w)
    if (w < wid) woff += wt[w];
  float p = __shfl_up(sc, 1);
  float run = woff + (lane ? p : 0.f);
  if (br) {
    float* pb = PreB + (size_t)c * SP;
#pragma unroll
    for (int e = 0; e < 16; ++e) {
      pb[qb + e] = run;
      run += vals[e];
    }
    if (t == 511) pb[NROW] = run;
  } else {
    float* sa = SufA + (size_t)c * SP;
#pragma unroll
    for (int e = 0; e < 16; ++e) {
      run += vals[e];
      sa[NROW - 1 - (qb + e)] = run;
    }
    if (t == 0) sa[NROW] = 0.f;
  }
}

// K5: per-row closed-form softmax combine + residual + W_f/lrelu + W_o
__global__ void k_final(const float* __restrict__ h, const float* __restrict__ s1s,
                        const float* __restrict__ s2, const float* __restrict__ SufA,
                        const float* __restrict__ PreB, const unsigned* __restrict__ m1slot,
                        const float* __restrict__ Wf, const float* __restrict__ bf,
                        const float* __restrict__ Wo, const float* __restrict__ bo,
                        float* __restrict__ out) {
  int t = threadIdx.x;
  int lane = t & 63, wid = t >> 6;
  int i = blockIdx.x * 4 + wid;
  float M1 = dec(*m1slot);
  float s2i = s2[i];
  float th = -s2i;
  float z = s2i + M1;
  float mi = lrelu(z);
  float cA = __expf(z - mi);
  float cB = __expf(0.01f * s2i - mi);
  // wave-parallel lower_bound: cnt = #{ s1 < th }
  float v1 = s1s[lane * 128];
  int n1 = __popcll(__ballot(v1 < th));
  int cnt = 0;
  if (n1 > 0) {
    int L = (n1 - 1) * 128;
    float v2 = s1s[L + 1 + 2 * lane];
    int n2 = __popcll(__ballot(v2 < th));
    cnt = L + 2 * n2;
    if (cnt < NROW && s1s[cnt] < th) cnt++;
  }
  float vA = SufA[(size_t)lane * SP + cnt];
  float vB = PreB[(size_t)lane * SP + cnt];
  float zA = SufA[(size_t)64 * SP + cnt];
  float zB = PreB[(size_t)64 * SP + cnt];
  float Z = cA * zA + cB * zB;
  float h2 = (cA * vA + cB * vB) / Z + h[i * HD + lane];
  const float4* wrow = (const float4*)(Wf + lane * HD);
  float acc = bf[lane];
#pragma unroll
  for (int q = 0; q < 16; ++q) {
    float4 wv = wrow[q];
    int c = q * 4;
    acc += wv.x * __shfl(h2, c) + wv.y * __shfl(h2, c + 1) +
           wv.z * __shfl(h2, c + 2) + wv.w * __shfl(h2, c + 3);
  }
  float h3 = lrelu(acc);
  float pv = h3 * Wo[lane];
#pragma unroll
  for (int off = 32; off > 0; off >>= 1) pv += __shfl_xor(pv, off);
  if (lane == 0) out[i] = pv + bo[0];
}

extern "C" void kernel_launch(void* const* d_in, const int* in_sizes, int n_in,
                              void* d_out, int out_size, void* d_ws, size_t ws_size,
                              hipStream_t stream) {
  const float* x   = (const float*)d_in[0];
  const float* Wfc = (const float*)d_in[1];
  const float* bfc = (const float*)d_in[2];
  const float* Wtr = (const float*)d_in[3];
  const float* btr = (const float*)d_in[4];
  const float* a   = (const float*)d_in[5];
  const float* Wf  = (const float*)d_in[6];
  const float* bf  = (const float*)d_in[7];
  const float* Wo  = (const float*)d_in[8];
  const float* bo  = (const float*)d_in[9];
  float* out = (float*)d_out;

  char* w = (char*)d_ws;
  size_t off = 0;
  auto alloc = [&](size_t bytes) -> void* {
    void* p = w + off;
    off = (off + bytes + 255) & ~(size_t)255;
    return p;
  };
  float* h      = (float*)alloc((size_t)NROW * HD * 4);
  float* s1     = (float*)alloc(NROW * 4);
  float* s2     = (float*)alloc(NROW * 4);
  float* u12    = (float*)alloc(130 * 4);
  unsigned* m1  = (unsigned*)alloc(4);
  int* rank     = (int*)alloc(NROW * 4);
  int* inv      = (int*)alloc(NROW * 4);
  float* s1s    = (float*)alloc(NROW * 4);
  unsigned short* Wh = (unsigned short*)alloc((size_t)64 * WK * 2);
  unsigned short* Wl = (unsigned short*)alloc((size_t)64 * WK * 2);
  float* hsT    = (float*)alloc((size_t)HD * NROW * 4);
  float* SufA   = (float*)alloc((size_t)65 * SP * 4);
  float* PreB   = (float*)alloc((size_t)65 * SP * 4);
  (void)in_sizes; (void)n_in; (void)out_size; (void)ws_size;

  k_prep<<<1 + (64 * WK) / 256, 256, 0, stream>>>(Wtr, btr, a, Wfc, u12, m1, rank, Wh, Wl);
  k_gemm1<<<NROW / 32, 512, 0, stream>>>(x, Wh, Wl, bfc, h);
  k_hsv<<<NROW / 32, 256, 0, stream>>>(h, u12, s1, s2, m1);
  k_count<<<32 * 32, 256, 0, stream>>>(s1, rank);
  k_scatter<<<NROW / 256, 256, 0, stream>>>(s1, rank, inv, s1s);
  k_trans<<<NROW / 128, 256, 0, stream>>>(h, inv, hsT);
  k_scan<<<130, 512, 0, stream>>>(s1s, hsT, m1, SufA, PreB);
  k_final<<<NROW / 4, 256, 0, stream>>>(h, s1s, s2, SufA, PreB, m1, Wf, bf, Wo, bo, out);
}